// Round 6
// baseline (214.629 us; speedup 1.0000x reference)
//
#include <hip/hip_runtime.h>

#define THREADS 1024
#define BINS 4096
#define NCOPY 4
#define CAP 4096

__device__ __forceinline__ unsigned rotl32(unsigned x, unsigned r) {
  return (x << r) | (x >> (32u - r));
}

// Threefry-2x32, 20 rounds, key = (0, 42); returns x0 ^ x1 (the
// jax_threefry_partitionable=True 32-bit random_bits output).
// Partitionable path: counts = 64-bit flat iota as (hi, lo); n < 2^32 so hi = 0.
__device__ __forceinline__ unsigned threefry_xor_0_42(unsigned x0, unsigned x1) {
  const unsigned k0 = 0u, k1 = 42u, k2 = 0u ^ 42u ^ 0x1BD11BDAu;
  x0 += k0; x1 += k1;
#define TF_R(r) { x0 += x1; x1 = rotl32(x1, r); x1 ^= x0; }
  TF_R(13) TF_R(15) TF_R(26) TF_R(6)
  x0 += k1; x1 += k2 + 1u;
  TF_R(17) TF_R(29) TF_R(16) TF_R(24)
  x0 += k2; x1 += k0 + 2u;
  TF_R(13) TF_R(15) TF_R(26) TF_R(6)
  x0 += k0; x1 += k1 + 3u;
  TF_R(17) TF_R(29) TF_R(16) TF_R(24)
  x0 += k1; x1 += k2 + 4u;
  TF_R(13) TF_R(15) TF_R(26) TF_R(6)
  x0 += k2; x1 += k0 + 5u;
#undef TF_R
  return x0 ^ x1;
}

// Bit-exact replica of jax.random.gumbel(key(42), (B,V), f32)[flat] under
// jax_threefry_partitionable=True (JAX >= 0.4.30 default):
//   bits[j] = w0 ^ w1 of threefry2x32(key=(0,42), counts=(hi64(j)=0, lo64(j)=j))
__device__ __forceinline__ float gumbel_at(unsigned flat) {
  unsigned bits = threefry_xor_0_42(0u, flat);
  float fl = __uint_as_float((bits >> 9) | 0x3F800000u) - 1.0f;  // [0,1)
  const float tiny = 1.17549435e-38f;                            // finfo(f32).tiny
  float u = fmaxf(fl + tiny, tiny);  // == max(minval, fl*(1-tiny)+tiny) bitwise (1-tiny==1.0f)
  return -logf(-logf(u));            // logf -> __ocml_log_f32
}

// Monotone float <-> uint key (ascending order preserved), bijective.
__device__ __forceinline__ unsigned f2k(float f) {
  unsigned b = __float_as_uint(f);
  return (b & 0x80000000u) ? ~b : (b ^ 0x80000000u);
}
__device__ __forceinline__ float k2f(unsigned k) {
  unsigned b = (k & 0x80000000u) ? (k ^ 0x80000000u) : ~k;
  return __uint_as_float(b);
}

__global__ __launch_bounds__(THREADS) void sampler_kernel(
    const float* __restrict__ logits, const float* __restrict__ temps,
    const int* __restrict__ topk_ptr, int* __restrict__ out, int V) {
  const int row = blockIdx.x;
  const int tid = threadIdx.x;
  const unsigned K = (unsigned)(*topk_ptr);

  const float* rowp = logits + (size_t)row * (size_t)V;
  const float4* rowp4 = (const float4*)rowp;
  const int nv4 = V >> 2;

  __shared__ unsigned hist[NCOPY][BINS];   // 64 KB
  __shared__ unsigned cand_key[CAP];       // 16 KB
  __shared__ unsigned cand_idx[CAP];       // 16 KB
  __shared__ float    rv[THREADS];         // 4 KB
  __shared__ unsigned ri[THREADS];         // 4 KB
  __shared__ unsigned ncand, sBstar, sAbove, sK50;

  for (int i = tid; i < NCOPY * BINS; i += THREADS) ((unsigned*)hist)[i] = 0u;
  if (tid == 0) { ncand = 0u; sBstar = 0u; sAbove = 0u; sK50 = 0u; }
  __syncthreads();

  // ---- Phase A: histogram of top-12 monotone-key bits (4-way privatized) ----
  {
    unsigned* myh = hist[(tid >> 6) & (NCOPY - 1)];
    for (int i = tid; i < nv4; i += THREADS) {
      float4 v = rowp4[i];
      atomicAdd(&myh[f2k(v.x) >> 20], 1u);
      atomicAdd(&myh[f2k(v.y) >> 20], 1u);
      atomicAdd(&myh[f2k(v.z) >> 20], 1u);
      atomicAdd(&myh[f2k(v.w) >> 20], 1u);
    }
  }
  __syncthreads();

  // collapse copies into hist[0]
  for (int i = tid; i < BINS; i += THREADS) {
    unsigned s = hist[0][i];
#pragma unroll
    for (int cpy = 1; cpy < NCOPY; ++cpy) s += hist[cpy][i];
    hist[0][i] = s;
  }
  __syncthreads();

  // ---- Phase B: single-wave suffix scan; locate bin holding the K-th largest ----
  if (tid < 64) {
    const int lane = tid;
    unsigned s = 0;
    for (int k = 0; k < 64; ++k) s += hist[0][lane * 64 + k];
    unsigned suf = s;                       // inclusive suffix over 64-bin blocks
#pragma unroll
    for (int off = 1; off < 64; off <<= 1) {
      unsigned o = __shfl_down(suf, off);
      if (lane + off < 64) suf += o;
    }
    unsigned sufn = __shfl_down(suf, 1);    // suffix starting at lane+1's block
    if (lane == 63) sufn = 0u;
    if (suf >= K && sufn < K) {             // unique crossing lane
      unsigned run = sufn;
      for (int k = 63; k >= 0; --k) {
        unsigned h = hist[0][lane * 64 + k];
        unsigned nr = run + h;
        if (run < K && nr >= K) { sBstar = (unsigned)(lane * 64 + k); sAbove = run; }
        run = nr;
      }
    }
  }
  __syncthreads();

  const unsigned Bstar = sBstar;
  const unsigned cntAbove = sAbove;                       // #keys in bins > Bstar
  const unsigned long long binCeilP1 = ((unsigned long long)(Bstar + 1u)) << 20;
  const unsigned lowKey = (Bstar >= 1u) ? ((Bstar - 1u) << 20) : 0u;  // full extra bin of slack
  const float t = temps[row];
  const unsigned rowBase = (unsigned)row * (unsigned)V;

  float bestV = -INFINITY;
  unsigned bestI = 0xFFFFFFFFu;

  // ---- Phase C: re-scan (L3-resident). Sure winners direct; window buffered ----
  for (int i = tid; i < nv4; i += THREADS) {
    float4 v = rowp4[i];
    float f[4] = {v.x, v.y, v.z, v.w};
#pragma unroll
    for (int e = 0; e < 4; ++e) {
      unsigned key = f2k(f[e]);
      if (key < lowKey) continue;                    // ~99.8% early-out
      unsigned col = (unsigned)(i * 4 + e);
      if ((unsigned long long)key >= binCeilP1) {
        // key above all of bin Bstar => l > l50 => scaled >= kth (monotone division)
        float sj = f[e] / t;
        float val = sj + gumbel_at(rowBase + col);
        if (val > bestV || (val == bestV && col < bestI)) { bestV = val; bestI = col; }
      } else {
        unsigned p = atomicAdd(&ncand, 1u);
        if (p < CAP) { cand_key[p] = key; cand_idx[p] = col; }
      }
    }
  }
  __syncthreads();

  // ---- Phase D: exact K-th largest key among buffered, then masked Gumbel-argmax ----
  const unsigned c = min(ncand, (unsigned)CAP);
  for (unsigned i = tid; i < c; i += THREADS) {
    unsigned ki = cand_key[i];
    unsigned gt = 0, eq = 0;
    for (unsigned j = 0; j < c; ++j) {
      unsigned kj = cand_key[j];
      gt += (kj > ki) ? 1u : 0u;
      eq += (kj == ki) ? 1u : 0u;
    }
    // K-th largest overall sits at candidate-rank K-cntAbove-1 (0-indexed)
    if (cntAbove + gt < K && cntAbove + gt + eq >= K) sK50 = ki;  // same-value writers only
  }
  __syncthreads();

  const float l50 = k2f(sK50);
  const float s50 = l50 / t;  // exact fp32 division, identical op to reference kth
  for (unsigned i = tid; i < c; i += THREADS) {
    unsigned col = cand_idx[i];
    if (col >= (unsigned)V) continue;        // defensive
    float sj = k2f(cand_key[i]) / t;
    if (sj >= s50) {           // replicate `scaled < kth -> -inf` mask exactly
      float val = sj + gumbel_at(rowBase + col);
      if (val > bestV || (val == bestV && col < bestI)) { bestV = val; bestI = col; }
    }
  }

  // ---- Block argmax reduction, first-index tie-break (matches jnp.argmax) ----
  rv[tid] = bestV; ri[tid] = bestI;
  __syncthreads();
  for (int off = THREADS / 2; off > 0; off >>= 1) {
    if (tid < off) {
      float v2 = rv[tid + off]; unsigned i2 = ri[tid + off];
      if (v2 > rv[tid] || (v2 == rv[tid] && i2 < ri[tid])) { rv[tid] = v2; ri[tid] = i2; }
    }
    __syncthreads();
  }
  if (tid == 0) out[row] = (int)((ri[0] < (unsigned)V) ? ri[0] : 0u);
}

extern "C" void kernel_launch(void* const* d_in, const int* in_sizes, int n_in,
                              void* d_out, int out_size, void* d_ws, size_t ws_size,
                              hipStream_t stream) {
  const float* logits = (const float*)d_in[0];
  const float* temps  = (const float*)d_in[1];
  const int*   topk   = (const int*)d_in[2];
  int* out = (int*)d_out;

  const int B = in_sizes[1];              // 256
  const int V = in_sizes[0] / B;          // 128000

  sampler_kernel<<<B, THREADS, 0, stream>>>(logits, temps, topk, out, V);
}